// Round 1
// baseline (132.849 us; speedup 1.0000x reference)
//
#include <hip/hip_runtime.h>

#define HH 160
#define WW 160
#define DD 16
#define NG 8192
#define VOXEL 0.4f

// Packed per-Gaussian data in d_ws: 4 x float4 = 64 B each
//  p0 = (mu.x, mu.y, mu.z, opacity)
//  p1 = (3sx,  3sy,  3sz,  ci00)
//  p2 = (ci01, ci02, ci11, ci12)
//  p3 = (ci22, 0,    0,    0)

__global__ __launch_bounds__(256) void gv_precompute(
    const float* __restrict__ means, const float* __restrict__ opac,
    const float* __restrict__ scales, const float* __restrict__ rots,
    float4* __restrict__ pack) {
  int g = blockIdx.x * 256 + threadIdx.x;
  if (g >= NG) return;
  float qw = rots[g * 4 + 0], qx = rots[g * 4 + 1];
  float qy = rots[g * 4 + 2], qz = rots[g * 4 + 3];
  float inv = rsqrtf(qw * qw + qx * qx + qy * qy + qz * qz);
  qw *= inv; qx *= inv; qy *= inv; qz *= inv;
  float R[3][3];
  R[0][0] = 1.f - 2.f * (qy * qy + qz * qz);
  R[0][1] = 2.f * (qx * qy - qw * qz);
  R[0][2] = 2.f * (qx * qz + qw * qy);
  R[1][0] = 2.f * (qx * qy + qw * qz);
  R[1][1] = 1.f - 2.f * (qx * qx + qz * qz);
  R[1][2] = 2.f * (qy * qz - qw * qx);
  R[2][0] = 2.f * (qx * qz - qw * qy);
  R[2][1] = 2.f * (qy * qz + qw * qx);
  R[2][2] = 1.f - 2.f * (qx * qx + qy * qy);
  float sx = scales[g * 3 + 0], sy = scales[g * 3 + 1], sz = scales[g * 3 + 2];
  float s2[3] = {sx * sx, sy * sy, sz * sz};
  float is2[3] = {1.f / s2[0], 1.f / s2[1], 1.f / s2[2]};
  float cov00 = 0.f, cov11 = 0.f, cov22 = 0.f;
  float ci00 = 0.f, ci01 = 0.f, ci02 = 0.f, ci11 = 0.f, ci12 = 0.f, ci22 = 0.f;
#pragma unroll
  for (int c = 0; c < 3; c++) {
    cov00 += R[0][c] * R[0][c] * s2[c];
    cov11 += R[1][c] * R[1][c] * s2[c];
    cov22 += R[2][c] * R[2][c] * s2[c];
    ci00 += R[0][c] * R[0][c] * is2[c];
    ci01 += R[0][c] * R[1][c] * is2[c];
    ci02 += R[0][c] * R[2][c] * is2[c];
    ci11 += R[1][c] * R[1][c] * is2[c];
    ci12 += R[1][c] * R[2][c] * is2[c];
    ci22 += R[2][c] * R[2][c] * is2[c];
  }
  float4* p = pack + (size_t)g * 4;
  p[0] = make_float4(means[g * 3 + 0], means[g * 3 + 1], means[g * 3 + 2], opac[g]);
  p[1] = make_float4(3.f * sqrtf(cov00), 3.f * sqrtf(cov11), 3.f * sqrtf(cov22), ci00);
  p[2] = make_float4(ci01, ci02, ci11, ci12);
  p[3] = make_float4(ci22, 0.f, 0.f, 0.f);
}

// Tile = 8x8x4 voxels, 256 threads (one voxel each). Grid = (4, 20, 20).
__global__ __launch_bounds__(256) void gv_voxelize(
    const float4* __restrict__ pack, const float4* __restrict__ feats,
    float4* __restrict__ out) {
  __shared__ int s_cnt;
  __shared__ int s_idx[256];

  int tid = threadIdx.x;
  int dk = tid & 3, dj = (tid >> 2) & 7, di = tid >> 5;
  int tk = blockIdx.x, tj = blockIdx.y, ti = blockIdx.z;
  int i = ti * 8 + di, j = tj * 8 + dj, k = tk * 4 + dk;

  float px = (i + 0.5f) * VOXEL - 32.f;
  float py = (j + 0.5f) * VOXEL - 32.f;
  float pz = (k + 0.5f) * VOXEL - 1.f;

  // tile voxel-center bounds
  float cx0 = (ti * 8 + 0.5f) * VOXEL - 32.f, cx1 = cx0 + 7.f * VOXEL;
  float cy0 = (tj * 8 + 0.5f) * VOXEL - 32.f, cy1 = cy0 + 7.f * VOXEL;
  float cz0 = (tk * 4 + 0.5f) * VOXEL - 1.f,  cz1 = cz0 + 3.f * VOXEL;

  float4 acc[8];
#pragma unroll
  for (int f = 0; f < 8; f++) acc[f] = make_float4(0.f, 0.f, 0.f, 0.f);

  for (int base = 0; base < NG; base += 256) {
    __syncthreads();  // protect s_cnt/s_idx from previous iteration's readers
    if (tid == 0) s_cnt = 0;
    __syncthreads();

    int g = base + tid;
    float4 a = pack[(size_t)g * 4 + 0];
    float4 b = pack[(size_t)g * 4 + 1];
    bool ov = (a.x + b.x >= cx0) & (a.x - b.x <= cx1) &
              (a.y + b.y >= cy0) & (a.y - b.y <= cy1) &
              (a.z + b.z >= cz0) & (a.z - b.z <= cz1);
    if (ov) {
      int p = atomicAdd(&s_cnt, 1);
      s_idx[p] = g;
    }
    __syncthreads();
    int cnt = s_cnt;

    for (int n = 0; n < cnt; n++) {
      int gg = s_idx[n];
      const float4* p = pack + (size_t)gg * 4;
      float4 pa = p[0];
      float4 pb = p[1];
      float4 pc = p[2];
      float4 pd = p[3];
      float dx = px - pa.x, dy = py - pa.y, dz = pz - pa.z;
      bool in = (fabsf(dx) <= pb.x) & (fabsf(dy) <= pb.y) & (fabsf(dz) <= pb.z);
      if (__any(in)) {
        float maha = pb.w * dx * dx + pc.z * dy * dy + pd.x * dz * dz +
                     2.f * (pc.x * dx * dy + pc.y * dx * dz + pc.w * dy * dz);
        float w = in ? pa.w * __expf(-0.5f * maha) : 0.f;
        const float4* ft = feats + (size_t)gg * 8;
#pragma unroll
        for (int f = 0; f < 8; f++) {
          float4 fv = ft[f];
          acc[f].x += w * fv.x;
          acc[f].y += w * fv.y;
          acc[f].z += w * fv.z;
          acc[f].w += w * fv.w;
        }
      }
    }
  }

  size_t v = ((size_t)i * WW + j) * DD + k;
  float4* o = out + v * 8;
#pragma unroll
  for (int f = 0; f < 8; f++) o[f] = acc[f];
}

extern "C" void kernel_launch(void* const* d_in, const int* in_sizes, int n_in,
                              void* d_out, int out_size, void* d_ws, size_t ws_size,
                              hipStream_t stream) {
  const float* means  = (const float*)d_in[0];
  const float* opac   = (const float*)d_in[1];
  const float* scales = (const float*)d_in[2];
  const float* rots   = (const float*)d_in[3];
  const float4* feats = (const float4*)d_in[4];
  float4* pack = (float4*)d_ws;  // 8192 * 64 B = 512 KB

  gv_precompute<<<32, 256, 0, stream>>>(means, opac, scales, rots, pack);
  dim3 grid(4, 20, 20);
  gv_voxelize<<<grid, 256, 0, stream>>>(pack, feats, (float4*)d_out);
}

// Round 2
// 128.132 us; speedup vs baseline: 1.0368x; 1.0368x over previous
//
#include <hip/hip_runtime.h>

#define HH 160
#define WW 160
#define DD 16
#define NG 8192
#define VOXEL 0.4f

// tiles: 20 x 20 x 4 (each 8x8x4 voxels) = 1600 tiles
#define TTX 20
#define TTY 20
#define TTZ 4
#define NTILES (TTX * TTY * TTZ)
#define CAP 256   // max survivors per tile (expected ~44, Poisson max ~90)

// d_ws layout:
//   pack     : 8192 * 4 float4 (64 B/gaussian)           = 512 KB
//   tileCnt  : NTILES int                                 @ 512 KB
//   tileList : NTILES * CAP int                           @ 520 KB (1.6 MB)
// pack per gaussian:
//   p0 = (mu.x, mu.y, mu.z, opacity)
//   p1 = (3sx,  3sy,  3sz,  ci00)
//   p2 = (ci01, ci02, ci11, ci12)
//   p3 = (ci22, 0, 0, 0)

__global__ __launch_bounds__(256) void gv_precompute_bin(
    const float* __restrict__ means, const float* __restrict__ opac,
    const float* __restrict__ scales, const float* __restrict__ rots,
    float4* __restrict__ pack, int* __restrict__ tileCnt,
    int* __restrict__ tileList) {
  int g = blockIdx.x * 256 + threadIdx.x;
  if (g >= NG) return;
  float qw = rots[g * 4 + 0], qx = rots[g * 4 + 1];
  float qy = rots[g * 4 + 2], qz = rots[g * 4 + 3];
  float inv = rsqrtf(qw * qw + qx * qx + qy * qy + qz * qz);
  qw *= inv; qx *= inv; qy *= inv; qz *= inv;
  float R[3][3];
  R[0][0] = 1.f - 2.f * (qy * qy + qz * qz);
  R[0][1] = 2.f * (qx * qy - qw * qz);
  R[0][2] = 2.f * (qx * qz + qw * qy);
  R[1][0] = 2.f * (qx * qy + qw * qz);
  R[1][1] = 1.f - 2.f * (qx * qx + qz * qz);
  R[1][2] = 2.f * (qy * qz - qw * qx);
  R[2][0] = 2.f * (qx * qz - qw * qy);
  R[2][1] = 2.f * (qy * qz + qw * qx);
  R[2][2] = 1.f - 2.f * (qx * qx + qy * qy);
  float sx = scales[g * 3 + 0], sy = scales[g * 3 + 1], sz = scales[g * 3 + 2];
  float s2[3] = {sx * sx, sy * sy, sz * sz};
  float is2[3] = {1.f / s2[0], 1.f / s2[1], 1.f / s2[2]};
  float cov00 = 0.f, cov11 = 0.f, cov22 = 0.f;
  float ci00 = 0.f, ci01 = 0.f, ci02 = 0.f, ci11 = 0.f, ci12 = 0.f, ci22 = 0.f;
#pragma unroll
  for (int c = 0; c < 3; c++) {
    cov00 += R[0][c] * R[0][c] * s2[c];
    cov11 += R[1][c] * R[1][c] * s2[c];
    cov22 += R[2][c] * R[2][c] * s2[c];
    ci00 += R[0][c] * R[0][c] * is2[c];
    ci01 += R[0][c] * R[1][c] * is2[c];
    ci02 += R[0][c] * R[2][c] * is2[c];
    ci11 += R[1][c] * R[1][c] * is2[c];
    ci12 += R[1][c] * R[2][c] * is2[c];
    ci22 += R[2][c] * R[2][c] * is2[c];
  }
  float mx = means[g * 3 + 0], my = means[g * 3 + 1], mz = means[g * 3 + 2];
  float bx = 3.f * sqrtf(cov00), by = 3.f * sqrtf(cov11), bz = 3.f * sqrtf(cov22);
  float4* p = pack + (size_t)g * 4;
  p[0] = make_float4(mx, my, mz, opac[g]);
  p[1] = make_float4(bx, by, bz, ci00);
  p[2] = make_float4(ci01, ci02, ci11, ci12);
  p[3] = make_float4(ci22, 0.f, 0.f, 0.f);

  // voxel-center index ranges covered by bbox (with float-slop margin)
  const float eps = 1e-4f;
  int i0 = (int)ceilf((mx - bx + 32.f) * 2.5f - 0.5f - eps);
  int i1 = (int)floorf((mx + bx + 32.f) * 2.5f - 0.5f + eps);
  int j0 = (int)ceilf((my - by + 32.f) * 2.5f - 0.5f - eps);
  int j1 = (int)floorf((my + by + 32.f) * 2.5f - 0.5f + eps);
  int k0 = (int)ceilf((mz - bz + 1.f) * 2.5f - 0.5f - eps);
  int k1 = (int)floorf((mz + bz + 1.f) * 2.5f - 0.5f + eps);
  i0 = max(i0, 0); i1 = min(i1, HH - 1);
  j0 = max(j0, 0); j1 = min(j1, WW - 1);
  k0 = max(k0, 0); k1 = min(k1, DD - 1);
  if (i0 > i1 || j0 > j1 || k0 > k1) return;
  int ti0 = i0 >> 3, ti1 = i1 >> 3;
  int tj0 = j0 >> 3, tj1 = j1 >> 3;
  int tk0 = k0 >> 2, tk1 = k1 >> 2;
  for (int ti = ti0; ti <= ti1; ti++)
    for (int tj = tj0; tj <= tj1; tj++)
      for (int tk = tk0; tk <= tk1; tk++) {
        int t = (ti * TTY + tj) * TTZ + tk;
        int pos = atomicAdd(&tileCnt[t], 1);
        if (pos < CAP) tileList[t * CAP + pos] = g;
      }
}

#define CHUNK_SZ 64

__global__ __launch_bounds__(256) void gv_voxelize(
    const float4* __restrict__ pack, const float4* __restrict__ feats,
    const int* __restrict__ tileCnt, const int* __restrict__ tileList,
    float4* __restrict__ out) {
  __shared__ float4 s_pack[CHUNK_SZ * 4];   // 4 KB
  __shared__ float4 s_feat[CHUNK_SZ * 8];   // 8 KB

  int tid = threadIdx.x;
  int dk = tid & 3, dj = (tid >> 2) & 7, di = tid >> 5;
  int tk = blockIdx.x, tj = blockIdx.y, ti = blockIdx.z;
  int i = ti * 8 + di, j = tj * 8 + dj, k = tk * 4 + dk;

  float px = (i + 0.5f) * VOXEL - 32.f;
  float py = (j + 0.5f) * VOXEL - 32.f;
  float pz = (k + 0.5f) * VOXEL - 1.f;

  int t = (ti * TTY + tj) * TTZ + tk;
  int cnt = tileCnt[t];
  cnt = min(cnt, CAP);
  const int* lst = tileList + t * CAP;

  float4 acc[8];
#pragma unroll
  for (int f = 0; f < 8; f++) acc[f] = make_float4(0.f, 0.f, 0.f, 0.f);

  for (int base = 0; base < cnt; base += CHUNK_SZ) {
    int M = min(CHUNK_SZ, cnt - base);
    __syncthreads();  // protect LDS from previous chunk's readers
    // stage pack: 1 float4 per thread
    {
      int m = tid >> 2, w = tid & 3;
      if (m < M) {
        int gg = lst[base + m];
        s_pack[m * 4 + w] = pack[(size_t)gg * 4 + w];
      }
    }
    // stage feats: 2 float4 per thread
#pragma unroll
    for (int r = 0; r < 2; r++) {
      int idx = tid + 256 * r;
      int m = idx >> 3, f = idx & 7;
      if (m < M) {
        int gg = lst[base + m];
        s_feat[m * 8 + f] = feats[(size_t)gg * 8 + f];
      }
    }
    __syncthreads();

    for (int n = 0; n < M; n++) {
      float4 pa = s_pack[n * 4 + 0];
      float4 pb = s_pack[n * 4 + 1];
      float dx = px - pa.x, dy = py - pa.y, dz = pz - pa.z;
      bool in = (fabsf(dx) <= pb.x) & (fabsf(dy) <= pb.y) & (fabsf(dz) <= pb.z);
      if (__any(in)) {
        float4 pc = s_pack[n * 4 + 2];
        float4 pd = s_pack[n * 4 + 3];
        float maha = pb.w * dx * dx + pc.z * dy * dy + pd.x * dz * dz +
                     2.f * (pc.x * dx * dy + pc.y * dx * dz + pc.w * dy * dz);
        float w = in ? pa.w * __expf(-0.5f * maha) : 0.f;
#pragma unroll
        for (int f = 0; f < 8; f++) {
          float4 fv = s_feat[n * 8 + f];
          acc[f].x += w * fv.x;
          acc[f].y += w * fv.y;
          acc[f].z += w * fv.z;
          acc[f].w += w * fv.w;
        }
      }
    }
  }

  size_t v = ((size_t)i * WW + j) * DD + k;
  float4* o = out + v * 8;
#pragma unroll
  for (int f = 0; f < 8; f++) o[f] = acc[f];
}

extern "C" void kernel_launch(void* const* d_in, const int* in_sizes, int n_in,
                              void* d_out, int out_size, void* d_ws, size_t ws_size,
                              hipStream_t stream) {
  const float* means  = (const float*)d_in[0];
  const float* opac   = (const float*)d_in[1];
  const float* scales = (const float*)d_in[2];
  const float* rots   = (const float*)d_in[3];
  const float4* feats = (const float4*)d_in[4];

  char* ws = (char*)d_ws;
  float4* pack   = (float4*)ws;                       // 512 KB
  int* tileCnt   = (int*)(ws + 512 * 1024);           // 6.4 KB
  int* tileList  = (int*)(ws + 520 * 1024);           // 1.6 MB

  hipMemsetAsync(tileCnt, 0, NTILES * sizeof(int), stream);
  gv_precompute_bin<<<32, 256, 0, stream>>>(means, opac, scales, rots,
                                            pack, tileCnt, tileList);
  dim3 grid(TTZ, TTY, TTX);
  gv_voxelize<<<grid, 256, 0, stream>>>(pack, feats, tileCnt, tileList,
                                        (float4*)d_out);
}